// Round 10
// baseline (120.796 us; speedup 1.0000x reference)
//
#include <hip/hip_runtime.h>
#include <hip/hip_bf16.h>
#include <math.h>

#define MDIM 8192
#define NDIM 4096
#define KDIM 128

typedef __bf16 bf16x8 __attribute__((ext_vector_type(8)));
typedef float f32x4 __attribute__((ext_vector_type(4)));

__device__ __forceinline__ unsigned short f32_to_bf16_rne(float f) {
  unsigned int u = __float_as_uint(f);
  u += 0x7fffu + ((u >> 16) & 1u);
  return (unsigned short)(u >> 16);
}

// Convert f32 -> bf16 (vectorized), and compute sum of squares (for ||U||_F, ||V||_F)
__global__ void convert_kernel(const float* __restrict__ X, unsigned short* __restrict__ Xb,
                               double* __restrict__ partial, int n4) {
  int tid = blockIdx.x * blockDim.x + threadIdx.x;
  int stride = gridDim.x * blockDim.x;
  float s = 0.f;
  const float4* X4 = (const float4*)X;
  ushort4* Xb4 = (ushort4*)Xb;
  for (int i = tid; i < n4; i += stride) {
    float4 v = X4[i];
    s += v.x * v.x + v.y * v.y + v.z * v.z + v.w * v.w;
    ushort4 p;
    p.x = f32_to_bf16_rne(v.x);
    p.y = f32_to_bf16_rne(v.y);
    p.z = f32_to_bf16_rne(v.z);
    p.w = f32_to_bf16_rne(v.w);
    Xb4[i] = p;
  }
  for (int off = 32; off > 0; off >>= 1) s += __shfl_down(s, off, 64);
  __shared__ float sw[4];
  int lane = threadIdx.x & 63, wid = threadIdx.x >> 6;
  if (lane == 0) sw[wid] = s;
  __syncthreads();
  if (threadIdx.x == 0) partial[blockIdx.x] = (double)(sw[0] + sw[1] + sw[2] + sw[3]);
}

// ALL THREE fused products, one 128x64 tile per block (48KB LDS -> 3 blocks/CU):
//   g in [0,4096):        (Ub Vb^T vs A  )   64 block-cols, ldT=4096
//   g in [4096,12288):    (Ub Ub^T vs S_m)  128 block-cols, ldT=8192
//   g in [12288,14336):   (Vb Vb^T vs S_d)   64 block-cols, ldT=4096
//
// R9 established (184->111us): all global accesses must be wave-contiguous
// full 128B lines, MFMA operands via LDS (lgkmcnt, never drains the T queue).
// R10: tile 128x128 -> 128x64 cuts LDS 64KB -> 48KB => 3 blocks/CU (was 2),
// 12 waves/CU: one more phase-offset block per CU to keep T loads in flight
// during the other blocks' MFMA/compare windows. Panel:T ratio 1.5:1 (L2-fed).
__global__ __launch_bounds__(256, 3) void fused_all(
    const unsigned short* __restrict__ Ub,  // [M][128] bf16 bits
    const unsigned short* __restrict__ Vb,  // [N][128] bf16 bits
    const float* __restrict__ A,
    const float* __restrict__ S_m,
    const float* __restrict__ S_d,
    double* __restrict__ partial) {
  __shared__ float LDSf[12288];  // 48KB: X panel 0-32KB, Y panel 32-48KB; P overlays 0-32KB
  char* LDSc = (char*)LDSf;

  const int g = blockIdx.x;
  const unsigned short* Xb;
  const unsigned short* Yb;
  const float* T;
  int ldT, v, gc;
  if (g < 4096) {
    Xb = Ub; Yb = Vb; T = A; ldT = NDIM; v = g; gc = 64;
  } else if (g < 12288) {
    Xb = Ub; Yb = Ub; T = S_m; ldT = MDIM; v = g - 4096; gc = 128;
  } else {
    Xb = Vb; Yb = Vb; T = S_d; ldT = NDIM; v = g - 12288; gc = 64;
  }
  const int r_blk = v / gc;
  const int c_blk = v - r_blk * gc;
  const int brow = r_blk * 128, bcol = c_blk * 64;

  const int tid = threadIdx.x;
  const int lane = tid & 63;
  const int wid = tid >> 6;
  const int wr = wid >> 1, wc = wid & 1;  // wave tile: 64 rows x 32 cols
  const int l15 = lane & 15;
  const int lg = lane >> 4;

  // ---- 1) stage X (128 rows) + Y (64 rows) panels: wave-linear LDS dest,
  //         source chunk-XOR-swizzled (involution; frag reads use same XOR) ----
  {
    const int ro = lane >> 4;  // row within 4-row group
    const int j = lane & 15;   // 16B chunk within 256B row
#pragma unroll
    for (int i = 0; i < 8; ++i) {
      const int rl = i * 16 + wid * 4 + ro;
      const unsigned short* gp = Xb + (size_t)(brow + rl) * KDIM + ((j ^ (rl & 7)) << 3);
      __builtin_amdgcn_global_load_lds(
          (const __attribute__((address_space(1))) void*)gp,
          (__attribute__((address_space(3))) void*)(LDSc + (i * 16 + wid * 4) * 256), 16, 0, 0);
    }
#pragma unroll
    for (int i = 0; i < 4; ++i) {
      const int rl = i * 16 + wid * 4 + ro;
      const unsigned short* gp = Yb + (size_t)(bcol + rl) * KDIM + ((j ^ (rl & 7)) << 3);
      __builtin_amdgcn_global_load_lds(
          (const __attribute__((address_space(1))) void*)gp,
          (__attribute__((address_space(3))) void*)(LDSc + 32768 + (i * 16 + wid * 4) * 256), 16, 0, 0);
    }
  }
  __builtin_amdgcn_sched_barrier(0);

  // ---- 2) T tile -> registers, wave-contiguous (4 rows x 256B per instr) ----
  const f32x4* Tb = (const f32x4*)T + (size_t)brow * (ldT >> 2) + (bcol >> 2);
  const int ldT4 = ldT >> 2;
  const int tr = tid >> 4, tc = tid & 15;  // 16 rows x 16 chunks per instr
  f32x4 t[8];
#pragma unroll
  for (int it = 0; it < 8; ++it)
    t[it] = Tb[(size_t)(it * 16 + tr) * ldT4 + tc];
  __builtin_amdgcn_sched_barrier(0);

  // ---- panels done (8 T loads still in flight), all waves synced ----
  asm volatile("s_waitcnt vmcnt(8)" ::: "memory");
  __builtin_amdgcn_sched_barrier(0);
  __builtin_amdgcn_s_barrier();

  // ---- 3) MFMA phase: operands from LDS (lgkmcnt only) ----
  f32x4 acc[2][4] = {};  // acc[p][q][reg] = P[wr*64+q*16+l15][wc*32+p*16+lg*4+reg]
#pragma unroll
  for (int kk = 0; kk < 4; ++kk) {
    const int c = kk * 4 + lg;  // 16B chunk within 256B row
    bf16x8 y[2], x[4];
#pragma unroll
    for (int p = 0; p < 2; ++p) {
      const int rl = wc * 32 + p * 16 + l15;
      y[p] = *(const bf16x8*)(LDSc + 32768 + rl * 256 + ((c ^ (rl & 7)) << 4));
    }
#pragma unroll
    for (int q = 0; q < 4; ++q) {
      const int rl = wr * 64 + q * 16 + l15;
      x[q] = *(const bf16x8*)(LDSc + rl * 256 + ((c ^ (rl & 7)) << 4));
    }
#pragma unroll
    for (int p = 0; p < 2; ++p)
#pragma unroll
      for (int q = 0; q < 4; ++q)
        acc[p][q] = __builtin_amdgcn_mfma_f32_16x16x32_bf16(y[p], x[q], acc[p][q], 0, 0, 0);
  }

  // ---- 4) panels dead; overlay P (128 rows x 256B) into LDS, swizzled ----
  __syncthreads();
#pragma unroll
  for (int q = 0; q < 4; ++q) {
    const int rp = wr * 64 + q * 16 + l15;
#pragma unroll
    for (int p = 0; p < 2; ++p) {
      const int cw = wc * 8 + p * 4 + lg;  // 16B chunk within 256B row
      *(f32x4*)(LDSc + rp * 256 + ((cw ^ (rp & 7)) << 4)) = acc[p][q];
    }
  }
  __syncthreads();

  // ---- 5) compare: wave-contiguous LDS reads vs register T ----
  float s = 0.f;
#pragma unroll
  for (int it = 0; it < 8; ++it) {
    const int r = it * 16 + tr;
    const f32x4 pv = *(const f32x4*)(LDSc + r * 256 + ((tc ^ (r & 7)) << 4));
    const f32x4 d = pv - t[it];
    s += d[0] * d[0] + d[1] * d[1] + d[2] * d[2] + d[3] * d[3];
  }

  // deterministic block reduction
  for (int off = 32; off > 0; off >>= 1) s += __shfl_down(s, off, 64);
  __shared__ float swred[4];
  if (lane == 0) swred[wid] = s;
  __syncthreads();
  if (tid == 0)
    partial[g] = (double)(swred[0] + swred[1] + swred[2] + swred[3]);
}

// Deterministic final reduction of all partial arrays + scalar combine.
__global__ void finalize_kernel(const double* __restrict__ pr, int nr,
                                const double* __restrict__ psm, int nsm,
                                const double* __restrict__ psd, int nsd,
                                const double* __restrict__ pu, int nu,
                                const double* __restrict__ pv, int nv,
                                float* __restrict__ out) {
  __shared__ double sh[256];
  double sums[5];
  const double* ps[5] = {pr, psm, psd, pu, pv};
  int ns[5] = {nr, nsm, nsd, nu, nv};
  for (int q = 0; q < 5; ++q) {
    double s = 0.0;
    for (int i = threadIdx.x; i < ns[q]; i += 256) s += ps[q][i];
    sh[threadIdx.x] = s;
    __syncthreads();
    for (int k = 128; k > 0; k >>= 1) {
      if (threadIdx.x < k) sh[threadIdx.x] += sh[threadIdx.x + k];
      __syncthreads();
    }
    sums[q] = sh[0];
    __syncthreads();
  }
  if (threadIdx.x == 0) {
    double recon = sums[0] / ((double)MDIM * (double)NDIM);
    double res = recon + 0.01 * (sqrt(sums[3]) + sqrt(sums[4]) + sqrt(sums[1]) + sqrt(sums[2]));
    out[0] = (float)res;
  }
}

extern "C" void kernel_launch(void* const* d_in, const int* in_sizes, int n_in,
                              void* d_out, int out_size, void* d_ws, size_t ws_size,
                              hipStream_t stream) {
  const float* A   = (const float*)d_in[0];  // [M][N]
  const float* S_m = (const float*)d_in[1];  // [M][M]
  const float* S_d = (const float*)d_in[2];  // [N][N]
  const float* U   = (const float*)d_in[3];  // [M][K]
  const float* V   = (const float*)d_in[4];  // [N][K]

  char* ws = (char*)d_ws;
  unsigned short* Ub = (unsigned short*)ws;                             // 2 MB
  unsigned short* Vb = (unsigned short*)(ws + (size_t)2 * 1024 * 1024); // 1 MB
  double* pd = (double*)(ws + (size_t)3 * 1024 * 1024);
  double* p_all = pd;            // 14336: [0,4096) recon | [4096,12288) S_m | [12288,14336) S_d
  double* p_u   = p_all + 14336; // 256
  double* p_v   = p_u + 256;     // 256

  convert_kernel<<<256, 256, 0, stream>>>(U, Ub, p_u, MDIM * KDIM / 4);
  convert_kernel<<<256, 256, 0, stream>>>(V, Vb, p_v, NDIM * KDIM / 4);

  fused_all<<<14336, 256, 0, stream>>>(Ub, Vb, A, S_m, S_d, p_all);

  finalize_kernel<<<1, 256, 0, stream>>>(p_all, 4096, p_all + 4096, 8192, p_all + 12288, 2048,
                                         p_u, 256, p_v, 256, (float*)d_out);
}